// Round 6
// baseline (567.680 us; speedup 1.0000x reference)
//
#include <hip/hip_runtime.h>
#include <stdint.h>

// ---------------------------------------------------------------------------
// RPN loss: IoU>0.7 matching + argmax fix + exact JAX threefry sampling
// (partitionable PRNG path) + smooth-L1 + BCE, all on device.
// R1: k_scanloc serial tail -> LDS cum + parallel search (2785->1408us).
// R2: k_gather latency fix (binslot in LDS, range reservation) (1408->770us).
// R3: k_iou LDS atomicMax CAS storm -> wave butterfly+ballot (770->595us).
// R4: k_collect 1-block stream -> k_cnt/k_setup/k_emit; passclear folded
//     into scanloc/bsort (595->499us).
// R5: k_bsort was a 55-66-stage bitonic at 1 wave/SIMD (barrier-latency
//     bound, 72us x6 = 435us). Replaced by k_select: radix-select on the
//     next 8 key bits (histogram + 8-barrier scan + ~4-elem sub-bucket
//     rank). O(n), ~12 barriers.
// ---------------------------------------------------------------------------

#define N_PRED   131072
#define NBOXK    64
#define NM_TOT   8388608u          // N_PRED * NBOXK
#define TCAP     65536
#define NBINS    8192
#define BINSHIFT 19                // key >> 19 -> 13-bit bin
#define SLOTCAP  3072
#define MAXSLOT  192
#define HCAP     2048              // per-block LDS hit buffer (gather)
#define CBLK     512               // collect blocks
#define CANDCAP  128               // sub-bucket candidate cap (lambda~4)

typedef unsigned long long ull;

struct WS {
  uint32_t P, M, n_pos, n_neg;
  uint32_t R[2];                   // shuffle rounds per chain (0=pos,1=neg)
  uint32_t S[2];                   // sizes per chain
  uint32_t kcnt[2];                // target counts per chain
  uint32_t sub[2][3][2];           // per-round subkeys
  uint32_t nslots;
  uint32_t pad_[31];
  ull      colBest[NBOXK];         // packed (iou_bits<<32)|~row
  ull      maskWords[N_PRED];      // 64 mask bits per pred row
  uint32_t T[TCAP];                // sorted flat positions of mask==true
  uint32_t tgt[2][256];            // current target ranks / positions
  uint32_t hist[NBINS];
  int32_t  binslot[NBINS];
  int32_t  tslot[256];
  uint32_t tlocal[256];
  uint32_t blockSum[CBLK];
  uint32_t blockBase[CBLK];
  uint32_t slotCnt[MAXSLOT];
  ull      slotBuf[MAXSLOT][SLOTCAP];
};

// Threefry-2x32-20, matches JAX reference implementation exactly.
__device__ __forceinline__ void tf2(uint32_t k0, uint32_t k1,
                                    uint32_t& x0, uint32_t& x1) {
  uint32_t ks[3] = {k0, k1, k0 ^ k1 ^ 0x1BD11BDAu};
  const uint32_t R0[4] = {13u, 15u, 26u, 6u};
  const uint32_t R1[4] = {17u, 29u, 16u, 24u};
  x0 += ks[0]; x1 += ks[1];
#pragma unroll
  for (int i = 0; i < 5; ++i) {
    const uint32_t* rr = (i & 1) ? R1 : R0;
#pragma unroll
    for (int j = 0; j < 4; ++j) {
      x0 += x1;
      x1 = (x1 << rr[j]) | (x1 >> (32u - rr[j]));
      x1 ^= x0;
    }
    x0 += ks[(i + 1) % 3];
    x1 += ks[(i + 2) % 3] + (uint32_t)(i + 1);
  }
}

// partitionable random_bits for 32-bit: xor of the two outputs, counter = pos
__device__ __forceinline__ uint32_t tf_bits(uint32_t k0, uint32_t k1, uint32_t p) {
  uint32_t a = 0u, b = p;
  tf2(k0, k1, a, b);
  return a ^ b;
}

__global__ void k_init(WS* ws) {
  int t = threadIdx.x;
  if (t < NBOXK) ws->colBest[t] = 0ull;
}

// IoU mask + per-column argmax via wave butterfly + ballot (no atomic storm).
// Bit-exact f32 (no FMA contraction). iou is never NaN (union > 0 always).
__global__ __launch_bounds__(256) void k_iou(const float4* __restrict__ pred,
                                             const float4* __restrict__ tgtb,
                                             WS* ws) {
  __shared__ float4 tb[NBOXK];
  __shared__ float ta[NBOXK];
  __shared__ ull cb[NBOXK];
  int tid = threadIdx.x;
  if (tid < NBOXK) {
    float4 b = tgtb[tid];
    tb[tid] = b;
    ta[tid] = __fmul_rn(__fsub_rn(b.z, b.x), __fsub_rn(b.w, b.y));
    cb[tid] = 0ull;
  }
  __syncthreads();
  int i = blockIdx.x * blockDim.x + tid;
  float4 p = pred[i];
  float pa = __fmul_rn(__fsub_rn(p.z, p.x), __fsub_rn(p.w, p.y));
  ull word = 0ull;
  int lane = tid & 63;
  uint32_t wavebase = (uint32_t)(blockIdx.x * blockDim.x) + (uint32_t)(tid & ~63);
  for (int c = 0; c < NBOXK; ++c) {
    float4 t = tb[c];
    float ltx = fmaxf(p.x, t.x), lty = fmaxf(p.y, t.y);
    float rbx = fminf(p.z, t.z), rby = fminf(p.w, t.w);
    float wx = fmaxf(__fsub_rn(rbx, ltx), 0.0f);
    float wy = fmaxf(__fsub_rn(rby, lty), 0.0f);
    float inter = __fmul_rn(wx, wy);
    float uni = __fsub_rn(__fadd_rn(pa, ta[c]), inter);
    float iou = __fdiv_rn(inter, uni);
    if (iou > 0.7f) word |= (1ull << c);
    float wm = iou;
#pragma unroll
    for (int off = 32; off > 0; off >>= 1)
      wm = fmaxf(wm, __shfl_xor(wm, off, 64));
    ull bal = __ballot(iou == wm);
    if (lane == 0) {
      uint32_t row = wavebase + (uint32_t)(__ffsll((long long)bal) - 1);
      ull pk = ((ull)__float_as_uint(wm) << 32) | (ull)(~row);
      atomicMax(&cb[c], pk);   // 4 waves -> 4-way contention only
    }
  }
  ws->maskWords[i] = word;
  __syncthreads();
  if (tid < NBOXK) atomicMax(&ws->colBest[tid], cb[tid]);
}

// need[c] = column max <= 0.7 -> set bit at first-argmax row (idempotent)
__global__ void k_fix(WS* ws) {
  int c = threadIdx.x;
  if (c < NBOXK) {
    ull pk = ws->colBest[c];
    float best = __uint_as_float((uint32_t)(pk >> 32));
    if (!(best > 0.7f)) {
      uint32_t row = ~(uint32_t)(pk & 0xFFFFFFFFu);
      atomicOr(&ws->maskWords[row], 1ull << c);
    }
  }
}

// Per-block popcount of mask rows -> blockSum.
__global__ __launch_bounds__(256) void k_cnt(WS* ws) {
  int t = threadIdx.x;
  int row = blockIdx.x * 256 + t;
  uint32_t c = (uint32_t)__popcll(ws->maskWords[row]);
  __shared__ uint32_t sm[256];
  sm[t] = c;
  __syncthreads();
  for (int off = 128; off > 0; off >>= 1) {
    if (t < off) sm[t] += sm[t + off];
    __syncthreads();
  }
  if (t == 0) ws->blockSum[blockIdx.x] = sm[0];
}

// Scan block sums + scalar/PRNG setup + initial hist/binslot clear.
__global__ __launch_bounds__(512) void k_setup(WS* ws) {
  __shared__ uint32_t sm[CBLK];
  int t = threadIdx.x;
  uint32_t c = ws->blockSum[t];
  sm[t] = c;
  __syncthreads();
  for (int off = 1; off < CBLK; off <<= 1) {
    uint32_t add = (t >= off) ? sm[t - off] : 0u;
    __syncthreads();
    sm[t] += add;
    __syncthreads();
  }
  ws->blockBase[t] = sm[t] - c;
  uint32_t total = sm[CBLK - 1];
  for (int i = t; i < NBINS; i += CBLK) { ws->hist[i] = 0u; ws->binslot[i] = -1; }
  if (t < MAXSLOT) ws->slotCnt[t] = 0u;
  if (t < 256) { ws->tgt[0][t] = (uint32_t)t; ws->tgt[1][t] = (uint32_t)t; }
  if (t == 0) {
    ws->nslots = 0u;
    uint32_t P = total < (uint32_t)TCAP ? total : (uint32_t)TCAP;
    uint32_t M = NM_TOT - P;
    uint32_t npos = P < 128u ? P : 128u;
    ws->P = P; ws->M = M;
    ws->n_pos = npos; ws->n_neg = 256u - npos;
    ws->S[0] = P; ws->S[1] = M;
    ws->kcnt[0] = npos; ws->kcnt[1] = 256u - npos;
    const double LOGU = 22.18070977791825;  // log(2^32 - 1)
    for (int d = 0; d < 2; ++d) {
      uint32_t Sd = ws->S[d];
      int R = 0;
      if (Sd > 1u) {
        R = (int)ceil(3.0 * log((double)Sd) / LOGU);
        if (R < 1) R = 1;
        if (R > 3) R = 3;
      }
      ws->R[d] = (uint32_t)R;
      uint32_t ck0, ck1;
      { uint32_t a = 0u, b = (uint32_t)d; tf2(0u, 42u, a, b); ck0 = a; ck1 = b; }
      for (int rr = 0; rr < 3; ++rr) {
        uint32_t s0 = 0u, s1 = 1u; tf2(ck0, ck1, s0, s1);
        ws->sub[d][rr][0] = s0; ws->sub[d][rr][1] = s1;
        uint32_t n0 = 0u, n1 = 0u; tf2(ck0, ck1, n0, n1);
        ck0 = n0; ck1 = n1;
      }
    }
  }
}

// Ordered emit of true positions (row-major, ascending bit), parallel.
__global__ __launch_bounds__(256) void k_emit(WS* ws) {
  int t = threadIdx.x;
  int row = blockIdx.x * 256 + t;
  ull w = ws->maskWords[row];
  uint32_t c = (uint32_t)__popcll(w);
  __shared__ uint32_t sm[256];
  sm[t] = c;
  __syncthreads();
  for (int off = 1; off < 256; off <<= 1) {
    uint32_t add = (t >= off) ? sm[t - off] : 0u;
    __syncthreads();
    sm[t] += add;
    __syncthreads();
  }
  uint32_t off0 = ws->blockBase[blockIdx.x] + sm[t] - c;
  while (w) {
    int bit = __ffsll((long long)w) - 1;
    w &= (w - 1);
    if (off0 < TCAP) ws->T[off0] = ((uint32_t)row << 6) | (uint32_t)bit;
    off0++;
  }
}

// 256 blocks x 1024 threads; unroll-2 independent threefry chains.
__global__ __launch_bounds__(1024) void k_hist(WS* ws, int d, int m) {
  int r = (int)ws->R[d] - m;
  if (r < 1) return;
  __shared__ uint32_t lh[NBINS];
  for (int i = threadIdx.x; i < NBINS; i += 1024) lh[i] = 0u;
  __syncthreads();
  uint32_t S = ws->S[d];
  uint32_t sk0 = ws->sub[d][r - 1][0], sk1 = ws->sub[d][r - 1][1];
  uint32_t stride = gridDim.x * blockDim.x;
  uint32_t j = blockIdx.x * blockDim.x + threadIdx.x;
  for (; j + stride < S; j += 2 * stride) {
    uint32_t k0 = tf_bits(sk0, sk1, j);
    uint32_t k1 = tf_bits(sk0, sk1, j + stride);
    atomicAdd(&lh[k0 >> BINSHIFT], 1u);
    atomicAdd(&lh[k1 >> BINSHIFT], 1u);
  }
  if (j < S) {
    uint32_t k0 = tf_bits(sk0, sk1, j);
    atomicAdd(&lh[k0 >> BINSHIFT], 1u);
  }
  __syncthreads();
  for (int i = threadIdx.x; i < NBINS; i += 1024) {
    uint32_t v = lh[i];
    if (v) atomicAdd(&ws->hist[i], v);
  }
}

// Scan hist in LDS; parallel per-target binary search; CAS-based slot dedup.
// Also clears slotCnt/nslots for this round's gather.
__global__ __launch_bounds__(1024) void k_scanloc(WS* ws, int d, int m) {
  int r = (int)ws->R[d] - m;
  if (r < 1) return;
  __shared__ uint32_t cumS[NBINS + 1];
  __shared__ uint32_t part[1024];
  int t = threadIdx.x;
  if (t == 0) ws->nslots = 0u;
  if (t < MAXSLOT) ws->slotCnt[t] = 0u;
  const int E = NBINS / 1024;  // 8
  uint32_t lv[E];
  uint32_t s = 0;
  uint32_t base = (uint32_t)t * E;
#pragma unroll
  for (int e = 0; e < E; ++e) { lv[e] = ws->hist[base + e]; s += lv[e]; }
  part[t] = s;
  __syncthreads();
  for (int off = 1; off < 1024; off <<= 1) {
    uint32_t add = (t >= off) ? part[t - off] : 0u;
    __syncthreads();
    part[t] += add;
    __syncthreads();
  }
  uint32_t run = part[t] - s;
#pragma unroll
  for (int e = 0; e < E; ++e) { cumS[base + e] = run; run += lv[e]; }
  if (t == 1023) cumS[NBINS] = run;
  __syncthreads();

  uint32_t k = ws->kcnt[d];
  uint32_t lo = 0;
  int old = 0;
  if (t < (int)k) {
    uint32_t tr = ws->tgt[d][t];
    uint32_t hi = NBINS;  // invariant: cumS[lo] <= tr < cumS[hi]
    while (hi - lo > 1u) {
      uint32_t mid = (lo + hi) >> 1;
      if (cumS[mid] <= tr) lo = mid; else hi = mid;
    }
    ws->tlocal[t] = tr - cumS[lo];
    old = atomicCAS(&ws->binslot[lo], -1, (int)(0x10000u + (uint32_t)t));
  }
  __syncthreads();
  if (t < (int)k && old == -1) {
    uint32_t slot = atomicAdd(&ws->nslots, 1u);
    ws->binslot[lo] = (int)slot;
  }
  __syncthreads();
  if (t < (int)k) ws->tslot[t] = ws->binslot[lo];
}

// binslot in LDS; hits buffered in LDS; per-slot range reservation.
__global__ __launch_bounds__(1024) void k_gather(WS* ws, int d, int m) {
  int r = (int)ws->R[d] - m;
  if (r < 1) return;
  __shared__ int bs[NBINS];            // 32KB
  __shared__ uint32_t hk[HCAP];        // 8KB
  __shared__ uint32_t hj[HCAP];        // 8KB
  __shared__ uint32_t scnt[MAXSLOT];
  __shared__ uint32_t sbase[MAXSLOT];
  __shared__ uint32_t scur[MAXSLOT];
  __shared__ uint32_t hcnt;
  int t = threadIdx.x;
  for (int i = t; i < NBINS; i += 1024) bs[i] = ws->binslot[i];
  if (t < MAXSLOT) scnt[t] = 0u;
  if (t == 0) hcnt = 0u;
  __syncthreads();
  uint32_t S = ws->S[d];
  uint32_t sk0 = ws->sub[d][r - 1][0], sk1 = ws->sub[d][r - 1][1];
  uint32_t stride = gridDim.x * blockDim.x;
  for (uint32_t j = blockIdx.x * blockDim.x + t; j < S; j += stride) {
    uint32_t kk = tf_bits(sk0, sk1, j);
    int sl = bs[kk >> BINSHIFT];
    if (sl >= 0) {
      uint32_t h = atomicAdd(&hcnt, 1u);
      if (h < HCAP) {
        hk[h] = kk; hj[h] = j;
        atomicAdd(&scnt[sl], 1u);
      } else {  // overflow fallback (statistically never)
        uint32_t idx = atomicAdd(&ws->slotCnt[sl], 1u);
        if (idx < SLOTCAP) ws->slotBuf[sl][idx] = ((ull)kk << 24) | (ull)j;
      }
    }
  }
  __syncthreads();
  if (t < MAXSLOT) {
    scur[t] = 0u;
    if (scnt[t]) sbase[t] = atomicAdd(&ws->slotCnt[t], scnt[t]);
  }
  __syncthreads();
  uint32_t n = hcnt < (uint32_t)HCAP ? hcnt : (uint32_t)HCAP;
  for (uint32_t h = t; h < n; h += 1024) {
    uint32_t kk = hk[h], j = hj[h];
    int sl = bs[kk >> BINSHIFT];
    uint32_t idx = sbase[sl] + atomicAdd(&scur[sl], 1u);
    if (idx < SLOTCAP) ws->slotBuf[sl][idx] = ((ull)kk << 24) | (ull)j;
  }
}

// Radix-select: rank-select the tlocal-th element of each needed bin WITHOUT
// sorting. One histogram pass on packed bits [35..42] (the 8 key bits below
// the bin bits; expected sub-bucket size ~4), 8-barrier scan, then rank the
// tiny sub-bucket by all-pairs comparison. Packed values are unique (pos is
// unique), so ranks are exact == stable sort order.
// Also stripes the hist/binslot clear for the NEXT round.
__global__ __launch_bounds__(256) void k_select(WS* ws, int d, int m) {
  int r = (int)ws->R[d] - m;
  if (r < 1) return;
  for (int i = blockIdx.x * 256 + threadIdx.x; i < NBINS; i += MAXSLOT * 256) {
    ws->hist[i] = 0u;
    ws->binslot[i] = -1;
  }
  int slot = blockIdx.x;
  if (slot >= (int)ws->nslots) return;
  int t = threadIdx.x;
  uint32_t cnt = ws->slotCnt[slot];
  if (cnt > SLOTCAP) cnt = SLOTCAP;

  __shared__ ull sh[SLOTCAP];          // 24KB
  __shared__ uint32_t hh[256];
  __shared__ uint32_t cum[257];
  __shared__ uint32_t tlist[256];
  __shared__ uint32_t ntgt;
  __shared__ ull cand[CANDCAP];
  __shared__ uint32_t candn;

  hh[t] = 0u;
  if (t == 0) ntgt = 0u;
  __syncthreads();
  for (uint32_t i = t; i < cnt; i += 256) {
    ull v = ws->slotBuf[slot][i];
    sh[i] = v;
    atomicAdd(&hh[(uint32_t)(v >> 35) & 255u], 1u);
  }
  uint32_t k = ws->kcnt[d];
  if (t < (int)k && ws->tslot[t] == slot) {
    uint32_t idx = atomicAdd(&ntgt, 1u);
    tlist[idx] = (uint32_t)t;
  }
  __syncthreads();
  // inclusive scan of hh -> cum[1..256]
  uint32_t v = hh[t];
  __shared__ uint32_t sb[256];
  sb[t] = v;
  __syncthreads();
  for (int off = 1; off < 256; off <<= 1) {
    uint32_t add = (t >= off) ? sb[t - off] : 0u;
    __syncthreads();
    sb[t] += add;
    __syncthreads();
  }
  if (t == 0) cum[0] = 0u;
  cum[t + 1] = sb[t];
  __syncthreads();

  uint32_t nt = ntgt;
  for (uint32_t q = 0; q < nt; ++q) {
    uint32_t sId = tlist[q];
    uint32_t tr = ws->tlocal[sId];
    uint32_t lo = 0, hi = 256;  // cum[lo] <= tr < cum[hi]
    while (hi - lo > 1u) {
      uint32_t mid = (lo + hi) >> 1;
      if (cum[mid] <= tr) lo = mid; else hi = mid;
    }
    uint32_t r2 = tr - cum[lo];
    if (t == 0) candn = 0u;
    __syncthreads();
    for (uint32_t i = t; i < cnt; i += 256) {
      ull vv = sh[i];
      if (((uint32_t)(vv >> 35) & 255u) == lo) {
        uint32_t ci = atomicAdd(&candn, 1u);
        if (ci < CANDCAP) cand[ci] = vv;
      }
    }
    __syncthreads();
    uint32_t cn = candn < (uint32_t)CANDCAP ? candn : (uint32_t)CANDCAP;
    if (t < (int)cn) {
      ull mine = cand[t];
      uint32_t rank = 0;
      for (uint32_t x = 0; x < cn; ++x) rank += (cand[x] < mine) ? 1u : 0u;
      if (rank == r2) ws->tgt[d][sId] = (uint32_t)(mine & 0xFFFFFFull);
    }
    __syncthreads();
  }
}

__device__ __forceinline__ float sl1(float dd) {
  float ad = fabsf(dd);
  return (ad < 1.0f) ? 0.5f * dd * dd : ad - 0.5f;
}

__global__ __launch_bounds__(256) void k_loss(WS* ws,
                                              const float* __restrict__ reg,
                                              const float* __restrict__ obj,
                                              const float4* __restrict__ tgtb,
                                              const float4* __restrict__ anch,
                                              float* out) {
  int s = threadIdx.x;
  uint32_t npos = ws->n_pos;
  double lr = 0.0, bc = 0.0;
  if (s < (int)npos) {
    uint32_t v = ws->tgt[0][s];
    uint32_t pa = ws->T[v];
    uint32_t i = pa >> 6, j = pa & 63u;
    float4 t = tgtb[j];
    float tcx = (t.x + t.z) * 0.5f, tcy = (t.y + t.w) * 0.5f;
    float tw = t.z - t.x, th = t.w - t.y;
    float4 a = anch[i];
    float r0 = (tcx - a.x) / a.z;
    float r1 = (tcy - a.y) / a.w;
    float r2 = logf(tw / a.z);
    float r3 = logf(th / a.w);
    lr = (double)sl1(reg[i * 4 + 0] - r0) + (double)sl1(reg[i * 4 + 1] - r1) +
         (double)sl1(reg[i * 4 + 2] - r2) + (double)sl1(reg[i * 4 + 3] - r3);
    float x = obj[i];
    bc = (double)(fmaxf(x, 0.0f) - x + log1pf(expf(-fabsf(x))));
  } else {
    uint32_t e = ws->tgt[1][s - (int)npos];
    uint32_t f = e;
    uint32_t P = ws->P;
    for (uint32_t q = 0; q < P; ++q) {
      if (ws->T[q] <= f) f++; else break;
    }
    uint32_t i = f >> 6;
    float x = obj[i];
    bc = (double)(fmaxf(x, 0.0f) + log1pf(expf(-fabsf(x))));
  }
  __shared__ double sA[256], sB[256];
  sA[s] = lr; sB[s] = bc;
  __syncthreads();
  for (int off = 128; off > 0; off >>= 1) {
    if (s < off) { sA[s] += sA[s + off]; sB[s] += sB[s + off]; }
    __syncthreads();
  }
  if (s == 0)
    out[0] = (float)(sA[0] * (10.0 / 2500.0) + sB[0] * (1.0 / 256.0));
}

extern "C" void kernel_launch(void* const* d_in, const int* in_sizes, int n_in,
                              void* d_out, int out_size, void* d_ws,
                              size_t ws_size, hipStream_t stream) {
  const float*  reg  = (const float*)d_in[0];
  const float*  obj  = (const float*)d_in[1];
  const float4* pred = (const float4*)d_in[2];
  const float4* tgtb = (const float4*)d_in[3];
  const float4* anch = (const float4*)d_in[4];
  float* out = (float*)d_out;
  WS* ws = (WS*)d_ws;
  (void)in_sizes; (void)n_in; (void)out_size; (void)ws_size;

  k_init<<<1, 64, 0, stream>>>(ws);
  k_iou<<<N_PRED / 256, 256, 0, stream>>>(pred, tgtb, ws);
  k_fix<<<1, 64, 0, stream>>>(ws);
  k_cnt<<<CBLK, 256, 0, stream>>>(ws);
  k_setup<<<1, 512, 0, stream>>>(ws);
  k_emit<<<CBLK, 256, 0, stream>>>(ws);
  for (int d = 0; d < 2; ++d) {
    for (int m = 0; m < 3; ++m) {
      k_hist<<<256, 1024, 0, stream>>>(ws, d, m);
      k_scanloc<<<1, 1024, 0, stream>>>(ws, d, m);
      k_gather<<<256, 1024, 0, stream>>>(ws, d, m);
      k_select<<<MAXSLOT, 256, 0, stream>>>(ws, d, m);
    }
  }
  k_loss<<<1, 256, 0, stream>>>(ws, reg, obj, tgtb, anch, out);
}

// Round 7
// 347.268 us; speedup vs baseline: 1.6347x; 1.6347x over previous
//
#include <hip/hip_runtime.h>
#include <stdint.h>

// ---------------------------------------------------------------------------
// RPN loss: IoU>0.7 matching + argmax fix + exact JAX threefry sampling
// (partitionable PRNG path) + smooth-L1 + BCE, all on device.
// R1: k_scanloc serial tail -> LDS cum + parallel search (2785->1408us).
// R2: k_gather latency fix (binslot in LDS, range reservation) (1408->770us).
// R3: k_iou LDS atomicMax CAS storm -> wave butterfly+ballot (770->595us).
// R4: k_collect 1-block stream -> k_cnt/k_setup/k_emit (595->499us).
// R5: k_bsort bitonic -> k_select radix-select. REGRESSED (499->568): first
//     neg round has sequential ranks 0..250 -> ALL targets in ONE bin ->
//     nslots=1, one block ran a 251-iteration serial q-loop (244us @ 0.1%
//     occupancy).
// R6: k_select rewritten: counting-sort by 8-bit subkey (hist+scan+scatter,
//     O(cnt)), then ALL targets resolve in parallel (one thread each:
//     binary search cum + rank within ~4-elem bucket). No serial q-loop.
// ---------------------------------------------------------------------------

#define N_PRED   131072
#define NBOXK    64
#define NM_TOT   8388608u          // N_PRED * NBOXK
#define TCAP     65536
#define NBINS    8192
#define BINSHIFT 19                // key >> 19 -> 13-bit bin
#define SLOTCAP  3072
#define MAXSLOT  192
#define HCAP     2048              // per-block LDS hit buffer (gather)
#define CBLK     512               // collect blocks

typedef unsigned long long ull;

struct WS {
  uint32_t P, M, n_pos, n_neg;
  uint32_t R[2];                   // shuffle rounds per chain (0=pos,1=neg)
  uint32_t S[2];                   // sizes per chain
  uint32_t kcnt[2];                // target counts per chain
  uint32_t sub[2][3][2];           // per-round subkeys
  uint32_t nslots;
  uint32_t pad_[31];
  ull      colBest[NBOXK];         // packed (iou_bits<<32)|~row
  ull      maskWords[N_PRED];      // 64 mask bits per pred row
  uint32_t T[TCAP];                // sorted flat positions of mask==true
  uint32_t tgt[2][256];            // current target ranks / positions
  uint32_t hist[NBINS];
  int32_t  binslot[NBINS];
  int32_t  tslot[256];
  uint32_t tlocal[256];
  uint32_t blockSum[CBLK];
  uint32_t blockBase[CBLK];
  uint32_t slotCnt[MAXSLOT];
  ull      slotBuf[MAXSLOT][SLOTCAP];
};

// Threefry-2x32-20, matches JAX reference implementation exactly.
__device__ __forceinline__ void tf2(uint32_t k0, uint32_t k1,
                                    uint32_t& x0, uint32_t& x1) {
  uint32_t ks[3] = {k0, k1, k0 ^ k1 ^ 0x1BD11BDAu};
  const uint32_t R0[4] = {13u, 15u, 26u, 6u};
  const uint32_t R1[4] = {17u, 29u, 16u, 24u};
  x0 += ks[0]; x1 += ks[1];
#pragma unroll
  for (int i = 0; i < 5; ++i) {
    const uint32_t* rr = (i & 1) ? R1 : R0;
#pragma unroll
    for (int j = 0; j < 4; ++j) {
      x0 += x1;
      x1 = (x1 << rr[j]) | (x1 >> (32u - rr[j]));
      x1 ^= x0;
    }
    x0 += ks[(i + 1) % 3];
    x1 += ks[(i + 2) % 3] + (uint32_t)(i + 1);
  }
}

// partitionable random_bits for 32-bit: xor of the two outputs, counter = pos
__device__ __forceinline__ uint32_t tf_bits(uint32_t k0, uint32_t k1, uint32_t p) {
  uint32_t a = 0u, b = p;
  tf2(k0, k1, a, b);
  return a ^ b;
}

__global__ void k_init(WS* ws) {
  int t = threadIdx.x;
  if (t < NBOXK) ws->colBest[t] = 0ull;
}

// IoU mask + per-column argmax via wave butterfly + ballot (no atomic storm).
// Bit-exact f32 (no FMA contraction). iou is never NaN (union > 0 always).
__global__ __launch_bounds__(256) void k_iou(const float4* __restrict__ pred,
                                             const float4* __restrict__ tgtb,
                                             WS* ws) {
  __shared__ float4 tb[NBOXK];
  __shared__ float ta[NBOXK];
  __shared__ ull cb[NBOXK];
  int tid = threadIdx.x;
  if (tid < NBOXK) {
    float4 b = tgtb[tid];
    tb[tid] = b;
    ta[tid] = __fmul_rn(__fsub_rn(b.z, b.x), __fsub_rn(b.w, b.y));
    cb[tid] = 0ull;
  }
  __syncthreads();
  int i = blockIdx.x * blockDim.x + tid;
  float4 p = pred[i];
  float pa = __fmul_rn(__fsub_rn(p.z, p.x), __fsub_rn(p.w, p.y));
  ull word = 0ull;
  int lane = tid & 63;
  uint32_t wavebase = (uint32_t)(blockIdx.x * blockDim.x) + (uint32_t)(tid & ~63);
  for (int c = 0; c < NBOXK; ++c) {
    float4 t = tb[c];
    float ltx = fmaxf(p.x, t.x), lty = fmaxf(p.y, t.y);
    float rbx = fminf(p.z, t.z), rby = fminf(p.w, t.w);
    float wx = fmaxf(__fsub_rn(rbx, ltx), 0.0f);
    float wy = fmaxf(__fsub_rn(rby, lty), 0.0f);
    float inter = __fmul_rn(wx, wy);
    float uni = __fsub_rn(__fadd_rn(pa, ta[c]), inter);
    float iou = __fdiv_rn(inter, uni);
    if (iou > 0.7f) word |= (1ull << c);
    float wm = iou;
#pragma unroll
    for (int off = 32; off > 0; off >>= 1)
      wm = fmaxf(wm, __shfl_xor(wm, off, 64));
    ull bal = __ballot(iou == wm);
    if (lane == 0) {
      uint32_t row = wavebase + (uint32_t)(__ffsll((long long)bal) - 1);
      ull pk = ((ull)__float_as_uint(wm) << 32) | (ull)(~row);
      atomicMax(&cb[c], pk);   // 4 waves -> 4-way contention only
    }
  }
  ws->maskWords[i] = word;
  __syncthreads();
  if (tid < NBOXK) atomicMax(&ws->colBest[tid], cb[tid]);
}

// need[c] = column max <= 0.7 -> set bit at first-argmax row (idempotent)
__global__ void k_fix(WS* ws) {
  int c = threadIdx.x;
  if (c < NBOXK) {
    ull pk = ws->colBest[c];
    float best = __uint_as_float((uint32_t)(pk >> 32));
    if (!(best > 0.7f)) {
      uint32_t row = ~(uint32_t)(pk & 0xFFFFFFFFu);
      atomicOr(&ws->maskWords[row], 1ull << c);
    }
  }
}

// Per-block popcount of mask rows -> blockSum.
__global__ __launch_bounds__(256) void k_cnt(WS* ws) {
  int t = threadIdx.x;
  int row = blockIdx.x * 256 + t;
  uint32_t c = (uint32_t)__popcll(ws->maskWords[row]);
  __shared__ uint32_t sm[256];
  sm[t] = c;
  __syncthreads();
  for (int off = 128; off > 0; off >>= 1) {
    if (t < off) sm[t] += sm[t + off];
    __syncthreads();
  }
  if (t == 0) ws->blockSum[blockIdx.x] = sm[0];
}

// Scan block sums + scalar/PRNG setup + initial hist/binslot clear.
__global__ __launch_bounds__(512) void k_setup(WS* ws) {
  __shared__ uint32_t sm[CBLK];
  int t = threadIdx.x;
  uint32_t c = ws->blockSum[t];
  sm[t] = c;
  __syncthreads();
  for (int off = 1; off < CBLK; off <<= 1) {
    uint32_t add = (t >= off) ? sm[t - off] : 0u;
    __syncthreads();
    sm[t] += add;
    __syncthreads();
  }
  ws->blockBase[t] = sm[t] - c;
  uint32_t total = sm[CBLK - 1];
  for (int i = t; i < NBINS; i += CBLK) { ws->hist[i] = 0u; ws->binslot[i] = -1; }
  if (t < MAXSLOT) ws->slotCnt[t] = 0u;
  if (t < 256) { ws->tgt[0][t] = (uint32_t)t; ws->tgt[1][t] = (uint32_t)t; }
  if (t == 0) {
    ws->nslots = 0u;
    uint32_t P = total < (uint32_t)TCAP ? total : (uint32_t)TCAP;
    uint32_t M = NM_TOT - P;
    uint32_t npos = P < 128u ? P : 128u;
    ws->P = P; ws->M = M;
    ws->n_pos = npos; ws->n_neg = 256u - npos;
    ws->S[0] = P; ws->S[1] = M;
    ws->kcnt[0] = npos; ws->kcnt[1] = 256u - npos;
    const double LOGU = 22.18070977791825;  // log(2^32 - 1)
    for (int d = 0; d < 2; ++d) {
      uint32_t Sd = ws->S[d];
      int R = 0;
      if (Sd > 1u) {
        R = (int)ceil(3.0 * log((double)Sd) / LOGU);
        if (R < 1) R = 1;
        if (R > 3) R = 3;
      }
      ws->R[d] = (uint32_t)R;
      uint32_t ck0, ck1;
      { uint32_t a = 0u, b = (uint32_t)d; tf2(0u, 42u, a, b); ck0 = a; ck1 = b; }
      for (int rr = 0; rr < 3; ++rr) {
        uint32_t s0 = 0u, s1 = 1u; tf2(ck0, ck1, s0, s1);
        ws->sub[d][rr][0] = s0; ws->sub[d][rr][1] = s1;
        uint32_t n0 = 0u, n1 = 0u; tf2(ck0, ck1, n0, n1);
        ck0 = n0; ck1 = n1;
      }
    }
  }
}

// Ordered emit of true positions (row-major, ascending bit), parallel.
__global__ __launch_bounds__(256) void k_emit(WS* ws) {
  int t = threadIdx.x;
  int row = blockIdx.x * 256 + t;
  ull w = ws->maskWords[row];
  uint32_t c = (uint32_t)__popcll(w);
  __shared__ uint32_t sm[256];
  sm[t] = c;
  __syncthreads();
  for (int off = 1; off < 256; off <<= 1) {
    uint32_t add = (t >= off) ? sm[t - off] : 0u;
    __syncthreads();
    sm[t] += add;
    __syncthreads();
  }
  uint32_t off0 = ws->blockBase[blockIdx.x] + sm[t] - c;
  while (w) {
    int bit = __ffsll((long long)w) - 1;
    w &= (w - 1);
    if (off0 < TCAP) ws->T[off0] = ((uint32_t)row << 6) | (uint32_t)bit;
    off0++;
  }
}

// 256 blocks x 1024 threads; unroll-2 independent threefry chains.
__global__ __launch_bounds__(1024) void k_hist(WS* ws, int d, int m) {
  int r = (int)ws->R[d] - m;
  if (r < 1) return;
  __shared__ uint32_t lh[NBINS];
  for (int i = threadIdx.x; i < NBINS; i += 1024) lh[i] = 0u;
  __syncthreads();
  uint32_t S = ws->S[d];
  uint32_t sk0 = ws->sub[d][r - 1][0], sk1 = ws->sub[d][r - 1][1];
  uint32_t stride = gridDim.x * blockDim.x;
  uint32_t j = blockIdx.x * blockDim.x + threadIdx.x;
  for (; j + stride < S; j += 2 * stride) {
    uint32_t k0 = tf_bits(sk0, sk1, j);
    uint32_t k1 = tf_bits(sk0, sk1, j + stride);
    atomicAdd(&lh[k0 >> BINSHIFT], 1u);
    atomicAdd(&lh[k1 >> BINSHIFT], 1u);
  }
  if (j < S) {
    uint32_t k0 = tf_bits(sk0, sk1, j);
    atomicAdd(&lh[k0 >> BINSHIFT], 1u);
  }
  __syncthreads();
  for (int i = threadIdx.x; i < NBINS; i += 1024) {
    uint32_t v = lh[i];
    if (v) atomicAdd(&ws->hist[i], v);
  }
}

// Scan hist in LDS; parallel per-target binary search; CAS-based slot dedup.
// Also clears slotCnt/nslots for this round's gather.
__global__ __launch_bounds__(1024) void k_scanloc(WS* ws, int d, int m) {
  int r = (int)ws->R[d] - m;
  if (r < 1) return;
  __shared__ uint32_t cumS[NBINS + 1];
  __shared__ uint32_t part[1024];
  int t = threadIdx.x;
  if (t == 0) ws->nslots = 0u;
  if (t < MAXSLOT) ws->slotCnt[t] = 0u;
  const int E = NBINS / 1024;  // 8
  uint32_t lv[E];
  uint32_t s = 0;
  uint32_t base = (uint32_t)t * E;
#pragma unroll
  for (int e = 0; e < E; ++e) { lv[e] = ws->hist[base + e]; s += lv[e]; }
  part[t] = s;
  __syncthreads();
  for (int off = 1; off < 1024; off <<= 1) {
    uint32_t add = (t >= off) ? part[t - off] : 0u;
    __syncthreads();
    part[t] += add;
    __syncthreads();
  }
  uint32_t run = part[t] - s;
#pragma unroll
  for (int e = 0; e < E; ++e) { cumS[base + e] = run; run += lv[e]; }
  if (t == 1023) cumS[NBINS] = run;
  __syncthreads();

  uint32_t k = ws->kcnt[d];
  uint32_t lo = 0;
  int old = 0;
  if (t < (int)k) {
    uint32_t tr = ws->tgt[d][t];
    uint32_t hi = NBINS;  // invariant: cumS[lo] <= tr < cumS[hi]
    while (hi - lo > 1u) {
      uint32_t mid = (lo + hi) >> 1;
      if (cumS[mid] <= tr) lo = mid; else hi = mid;
    }
    ws->tlocal[t] = tr - cumS[lo];
    old = atomicCAS(&ws->binslot[lo], -1, (int)(0x10000u + (uint32_t)t));
  }
  __syncthreads();
  if (t < (int)k && old == -1) {
    uint32_t slot = atomicAdd(&ws->nslots, 1u);
    ws->binslot[lo] = (int)slot;
  }
  __syncthreads();
  if (t < (int)k) ws->tslot[t] = ws->binslot[lo];
}

// binslot in LDS; hits buffered in LDS; per-slot range reservation.
__global__ __launch_bounds__(1024) void k_gather(WS* ws, int d, int m) {
  int r = (int)ws->R[d] - m;
  if (r < 1) return;
  __shared__ int bs[NBINS];            // 32KB
  __shared__ uint32_t hk[HCAP];        // 8KB
  __shared__ uint32_t hj[HCAP];        // 8KB
  __shared__ uint32_t scnt[MAXSLOT];
  __shared__ uint32_t sbase[MAXSLOT];
  __shared__ uint32_t scur[MAXSLOT];
  __shared__ uint32_t hcnt;
  int t = threadIdx.x;
  for (int i = t; i < NBINS; i += 1024) bs[i] = ws->binslot[i];
  if (t < MAXSLOT) scnt[t] = 0u;
  if (t == 0) hcnt = 0u;
  __syncthreads();
  uint32_t S = ws->S[d];
  uint32_t sk0 = ws->sub[d][r - 1][0], sk1 = ws->sub[d][r - 1][1];
  uint32_t stride = gridDim.x * blockDim.x;
  for (uint32_t j = blockIdx.x * blockDim.x + t; j < S; j += stride) {
    uint32_t kk = tf_bits(sk0, sk1, j);
    int sl = bs[kk >> BINSHIFT];
    if (sl >= 0) {
      uint32_t h = atomicAdd(&hcnt, 1u);
      if (h < HCAP) {
        hk[h] = kk; hj[h] = j;
        atomicAdd(&scnt[sl], 1u);
      } else {  // overflow fallback (statistically never)
        uint32_t idx = atomicAdd(&ws->slotCnt[sl], 1u);
        if (idx < SLOTCAP) ws->slotBuf[sl][idx] = ((ull)kk << 24) | (ull)j;
      }
    }
  }
  __syncthreads();
  if (t < MAXSLOT) {
    scur[t] = 0u;
    if (scnt[t]) sbase[t] = atomicAdd(&ws->slotCnt[t], scnt[t]);
  }
  __syncthreads();
  uint32_t n = hcnt < (uint32_t)HCAP ? hcnt : (uint32_t)HCAP;
  for (uint32_t h = t; h < n; h += 1024) {
    uint32_t kk = hk[h], j = hj[h];
    int sl = bs[kk >> BINSHIFT];
    uint32_t idx = sbase[sl] + atomicAdd(&scur[sl], 1u);
    if (idx < SLOTCAP) ws->slotBuf[sl][idx] = ((ull)kk << 24) | (ull)j;
  }
}

// Counting-sort by the 8-bit subkey (bits below the bin bits), then ALL
// targets of this slot resolve in parallel: one thread per target does a
// binary search on cum + exact rank within its ~4-element bucket (full
// packed-value compare => exact stable order; packed values are unique).
// Also stripes the hist/binslot clear for the NEXT round.
__global__ __launch_bounds__(256) void k_select(WS* ws, int d, int m) {
  int r = (int)ws->R[d] - m;
  if (r < 1) return;
  for (int i = blockIdx.x * 256 + threadIdx.x; i < NBINS; i += MAXSLOT * 256) {
    ws->hist[i] = 0u;
    ws->binslot[i] = -1;
  }
  int slot = blockIdx.x;
  if (slot >= (int)ws->nslots) return;
  int t = threadIdx.x;
  uint32_t cnt = ws->slotCnt[slot];
  if (cnt > SLOTCAP) cnt = SLOTCAP;

  __shared__ ull sh[SLOTCAP];          // 24KB raw
  __shared__ ull srt[SLOTCAP];         // 24KB bucket-grouped
  __shared__ uint32_t hh[256];
  __shared__ uint32_t cum[257];
  __shared__ uint32_t cur[256];
  __shared__ uint32_t sb[256];

  hh[t] = 0u;
  __syncthreads();
  for (uint32_t i = t; i < cnt; i += 256) {
    ull v = ws->slotBuf[slot][i];
    sh[i] = v;
    atomicAdd(&hh[(uint32_t)(v >> 35) & 255u], 1u);
  }
  __syncthreads();
  // inclusive scan of hh -> cum[1..256]
  sb[t] = hh[t];
  __syncthreads();
  for (int off = 1; off < 256; off <<= 1) {
    uint32_t add = (t >= off) ? sb[t - off] : 0u;
    __syncthreads();
    sb[t] += add;
    __syncthreads();
  }
  if (t == 0) cum[0] = 0u;
  cum[t + 1] = sb[t];
  cur[t] = 0u;
  __syncthreads();
  // counting scatter (unordered within bucket)
  for (uint32_t i = t; i < cnt; i += 256) {
    ull v = sh[i];
    uint32_t b = (uint32_t)(v >> 35) & 255u;
    uint32_t idx = cum[b] + atomicAdd(&cur[b], 1u);
    srt[idx] = v;
  }
  __syncthreads();
  // every target of this slot resolves independently, in parallel
  uint32_t k = ws->kcnt[d];
  if (t < (int)k && ws->tslot[t] == slot) {
    uint32_t tr = ws->tlocal[t];
    uint32_t lo = 0, hi = 256;  // invariant: cum[lo] <= tr < cum[hi]
    while (hi - lo > 1u) {
      uint32_t mid = (lo + hi) >> 1;
      if (cum[mid] <= tr) lo = mid; else hi = mid;
    }
    uint32_t r2 = tr - cum[lo];
    uint32_t b0 = cum[lo], b1 = cum[lo + 1];
    for (uint32_t x = b0; x < b1; ++x) {
      ull vx = srt[x];
      uint32_t rank = 0;
      for (uint32_t y = b0; y < b1; ++y) rank += (srt[y] < vx) ? 1u : 0u;
      if (rank == r2) { ws->tgt[d][t] = (uint32_t)(vx & 0xFFFFFFull); break; }
    }
  }
}

__device__ __forceinline__ float sl1(float dd) {
  float ad = fabsf(dd);
  return (ad < 1.0f) ? 0.5f * dd * dd : ad - 0.5f;
}

__global__ __launch_bounds__(256) void k_loss(WS* ws,
                                              const float* __restrict__ reg,
                                              const float* __restrict__ obj,
                                              const float4* __restrict__ tgtb,
                                              const float4* __restrict__ anch,
                                              float* out) {
  int s = threadIdx.x;
  uint32_t npos = ws->n_pos;
  double lr = 0.0, bc = 0.0;
  if (s < (int)npos) {
    uint32_t v = ws->tgt[0][s];
    uint32_t pa = ws->T[v];
    uint32_t i = pa >> 6, j = pa & 63u;
    float4 t = tgtb[j];
    float tcx = (t.x + t.z) * 0.5f, tcy = (t.y + t.w) * 0.5f;
    float tw = t.z - t.x, th = t.w - t.y;
    float4 a = anch[i];
    float r0 = (tcx - a.x) / a.z;
    float r1 = (tcy - a.y) / a.w;
    float r2 = logf(tw / a.z);
    float r3 = logf(th / a.w);
    lr = (double)sl1(reg[i * 4 + 0] - r0) + (double)sl1(reg[i * 4 + 1] - r1) +
         (double)sl1(reg[i * 4 + 2] - r2) + (double)sl1(reg[i * 4 + 3] - r3);
    float x = obj[i];
    bc = (double)(fmaxf(x, 0.0f) - x + log1pf(expf(-fabsf(x))));
  } else {
    uint32_t e = ws->tgt[1][s - (int)npos];
    uint32_t f = e;
    uint32_t P = ws->P;
    for (uint32_t q = 0; q < P; ++q) {
      if (ws->T[q] <= f) f++; else break;
    }
    uint32_t i = f >> 6;
    float x = obj[i];
    bc = (double)(fmaxf(x, 0.0f) + log1pf(expf(-fabsf(x))));
  }
  __shared__ double sA[256], sB[256];
  sA[s] = lr; sB[s] = bc;
  __syncthreads();
  for (int off = 128; off > 0; off >>= 1) {
    if (s < off) { sA[s] += sA[s + off]; sB[s] += sB[s + off]; }
    __syncthreads();
  }
  if (s == 0)
    out[0] = (float)(sA[0] * (10.0 / 2500.0) + sB[0] * (1.0 / 256.0));
}

extern "C" void kernel_launch(void* const* d_in, const int* in_sizes, int n_in,
                              void* d_out, int out_size, void* d_ws,
                              size_t ws_size, hipStream_t stream) {
  const float*  reg  = (const float*)d_in[0];
  const float*  obj  = (const float*)d_in[1];
  const float4* pred = (const float4*)d_in[2];
  const float4* tgtb = (const float4*)d_in[3];
  const float4* anch = (const float4*)d_in[4];
  float* out = (float*)d_out;
  WS* ws = (WS*)d_ws;
  (void)in_sizes; (void)n_in; (void)out_size; (void)ws_size;

  k_init<<<1, 64, 0, stream>>>(ws);
  k_iou<<<N_PRED / 256, 256, 0, stream>>>(pred, tgtb, ws);
  k_fix<<<1, 64, 0, stream>>>(ws);
  k_cnt<<<CBLK, 256, 0, stream>>>(ws);
  k_setup<<<1, 512, 0, stream>>>(ws);
  k_emit<<<CBLK, 256, 0, stream>>>(ws);
  for (int d = 0; d < 2; ++d) {
    for (int m = 0; m < 3; ++m) {
      k_hist<<<256, 1024, 0, stream>>>(ws, d, m);
      k_scanloc<<<1, 1024, 0, stream>>>(ws, d, m);
      k_gather<<<256, 1024, 0, stream>>>(ws, d, m);
      k_select<<<MAXSLOT, 256, 0, stream>>>(ws, d, m);
    }
  }
  k_loss<<<1, 256, 0, stream>>>(ws, reg, obj, tgtb, anch, out);
}

// Round 8
// 314.454 us; speedup vs baseline: 1.8053x; 1.1044x over previous
//
#include <hip/hip_runtime.h>
#include <stdint.h>

// ---------------------------------------------------------------------------
// RPN loss: IoU>0.7 matching + argmax fix + exact JAX threefry sampling
// (partitionable PRNG path) + smooth-L1 + BCE, all on device.
// R1: k_scanloc serial tail -> LDS cum + parallel search (2785->1408us).
// R2: k_gather latency fix (binslot in LDS, range reservation) (1408->770us).
// R3: k_iou LDS atomicMax CAS storm -> wave butterfly+ballot (770->595us).
// R4: k_collect 1-block stream -> k_cnt/k_setup/k_emit (595->499us).
// R5/R6: bitonic -> counting-sort select (499->347us).
// R7: k_iou butterfly was 384 dependent ds_permute/thread (40us). Now
//     lane-owns-column: row box via LDS broadcast, mask word = ballot,
//     per-lane argmax, zero shuffles. Hist caches u16 bin ids (ws is 256MB);
//     gather scans bin ids (16.8MB memory scan) and recomputes threefry only
//     for the ~1.8% hits after LDS compaction.
// ---------------------------------------------------------------------------

#define N_PRED   131072
#define NBOXK    64
#define NM_TOT   8388608u          // N_PRED * NBOXK
#define TCAP     65536
#define NBINS    8192
#define BINSHIFT 19                // key >> 19 -> 13-bit bin
#define SLOTCAP  3072
#define MAXSLOT  192
#define HCAP     2048              // per-block LDS hit buffer (gather)
#define CBLK     512               // collect blocks

typedef unsigned long long ull;

struct WS {
  uint32_t P, M, n_pos, n_neg;
  uint32_t R[2];                   // shuffle rounds per chain (0=pos,1=neg)
  uint32_t S[2];                   // sizes per chain
  uint32_t kcnt[2];                // target counts per chain
  uint32_t sub[2][3][2];           // per-round subkeys
  uint32_t nslots;
  uint32_t pad_[31];
  ull      colBest[NBOXK];         // packed (iou_bits<<32)|~row
  ull      maskWords[N_PRED];      // 64 mask bits per pred row
  uint32_t T[TCAP];                // sorted flat positions of mask==true
  uint32_t tgt[2][256];            // current target ranks / positions
  uint32_t hist[NBINS];
  int32_t  binslot[NBINS];
  int32_t  tslot[256];
  uint32_t tlocal[256];
  uint32_t blockSum[CBLK];
  uint32_t blockBase[CBLK];
  uint32_t slotCnt[MAXSLOT];
  ull      slotBuf[MAXSLOT][SLOTCAP];
  uint16_t binid[NM_TOT];          // 16.8MB bin-id cache (ws is 256MB)
};

// Threefry-2x32-20, matches JAX reference implementation exactly.
__device__ __forceinline__ void tf2(uint32_t k0, uint32_t k1,
                                    uint32_t& x0, uint32_t& x1) {
  uint32_t ks[3] = {k0, k1, k0 ^ k1 ^ 0x1BD11BDAu};
  const uint32_t R0[4] = {13u, 15u, 26u, 6u};
  const uint32_t R1[4] = {17u, 29u, 16u, 24u};
  x0 += ks[0]; x1 += ks[1];
#pragma unroll
  for (int i = 0; i < 5; ++i) {
    const uint32_t* rr = (i & 1) ? R1 : R0;
#pragma unroll
    for (int j = 0; j < 4; ++j) {
      x0 += x1;
      x1 = (x1 << rr[j]) | (x1 >> (32u - rr[j]));
      x1 ^= x0;
    }
    x0 += ks[(i + 1) % 3];
    x1 += ks[(i + 2) % 3] + (uint32_t)(i + 1);
  }
}

// partitionable random_bits for 32-bit: xor of the two outputs, counter = pos
__device__ __forceinline__ uint32_t tf_bits(uint32_t k0, uint32_t k1, uint32_t p) {
  uint32_t a = 0u, b = p;
  tf2(k0, k1, a, b);
  return a ^ b;
}

__global__ void k_init(WS* ws) {
  int t = threadIdx.x;
  if (t < NBOXK) ws->colBest[t] = 0ull;
}

// Lane l owns column l. Wave iterates its 64 rows: row box from LDS
// (wave-uniform broadcast), iou vs lane's column box, mask word via ballot
// (bit l == column l), per-lane running argmax (rows ascend => strict->
// earliest-row tie policy), one LDS atomicMax per lane (distinct addrs).
// Bit-exact f32 (no FMA contraction). iou never NaN (union > 0).
__global__ __launch_bounds__(256) void k_iou(const float4* __restrict__ pred,
                                             const float4* __restrict__ tgtb,
                                             WS* ws) {
  __shared__ float4 sp[256];
  __shared__ ull cb[NBOXK];
  int t = threadIdx.x;
  int lane = t & 63;
  int w = t >> 6;
  int rowBase = blockIdx.x * 256;
  sp[t] = pred[rowBase + t];
  if (t < NBOXK) cb[t] = 0ull;
  float4 tb = tgtb[lane];
  float ta = __fmul_rn(__fsub_rn(tb.z, tb.x), __fsub_rn(tb.w, tb.y));
  __syncthreads();
  ull myWord = 0ull;
  float bestI = -1.0f;
  uint32_t bestRow = 0u;
  int wbase = w * 64;
  for (int r = 0; r < 64; ++r) {
    float4 p = sp[wbase + r];
    float pa = __fmul_rn(__fsub_rn(p.z, p.x), __fsub_rn(p.w, p.y));
    float ltx = fmaxf(p.x, tb.x), lty = fmaxf(p.y, tb.y);
    float rbx = fminf(p.z, tb.z), rby = fminf(p.w, tb.w);
    float wx = fmaxf(__fsub_rn(rbx, ltx), 0.0f);
    float wy = fmaxf(__fsub_rn(rby, lty), 0.0f);
    float inter = __fmul_rn(wx, wy);
    float uni = __fsub_rn(__fadd_rn(pa, ta), inter);
    float iou = __fdiv_rn(inter, uni);
    ull bal = __ballot(iou > 0.7f);
    if (lane == r) myWord = bal;
    if (iou > bestI) { bestI = iou; bestRow = (uint32_t)(rowBase + wbase + r); }
  }
  ws->maskWords[rowBase + wbase + lane] = myWord;
  ull pk = ((ull)__float_as_uint(bestI) << 32) | (ull)(~bestRow);
  atomicMax(&cb[lane], pk);
  __syncthreads();
  if (t < NBOXK) atomicMax(&ws->colBest[t], cb[t]);
}

// need[c] = column max <= 0.7 -> set bit at first-argmax row (idempotent)
__global__ void k_fix(WS* ws) {
  int c = threadIdx.x;
  if (c < NBOXK) {
    ull pk = ws->colBest[c];
    float best = __uint_as_float((uint32_t)(pk >> 32));
    if (!(best > 0.7f)) {
      uint32_t row = ~(uint32_t)(pk & 0xFFFFFFFFu);
      atomicOr(&ws->maskWords[row], 1ull << c);
    }
  }
}

// Per-block popcount of mask rows -> blockSum.
__global__ __launch_bounds__(256) void k_cnt(WS* ws) {
  int t = threadIdx.x;
  int row = blockIdx.x * 256 + t;
  uint32_t c = (uint32_t)__popcll(ws->maskWords[row]);
  __shared__ uint32_t sm[256];
  sm[t] = c;
  __syncthreads();
  for (int off = 128; off > 0; off >>= 1) {
    if (t < off) sm[t] += sm[t + off];
    __syncthreads();
  }
  if (t == 0) ws->blockSum[blockIdx.x] = sm[0];
}

// Scan block sums + scalar/PRNG setup + initial hist/binslot clear.
__global__ __launch_bounds__(512) void k_setup(WS* ws) {
  __shared__ uint32_t sm[CBLK];
  int t = threadIdx.x;
  uint32_t c = ws->blockSum[t];
  sm[t] = c;
  __syncthreads();
  for (int off = 1; off < CBLK; off <<= 1) {
    uint32_t add = (t >= off) ? sm[t - off] : 0u;
    __syncthreads();
    sm[t] += add;
    __syncthreads();
  }
  ws->blockBase[t] = sm[t] - c;
  uint32_t total = sm[CBLK - 1];
  for (int i = t; i < NBINS; i += CBLK) { ws->hist[i] = 0u; ws->binslot[i] = -1; }
  if (t < MAXSLOT) ws->slotCnt[t] = 0u;
  if (t < 256) { ws->tgt[0][t] = (uint32_t)t; ws->tgt[1][t] = (uint32_t)t; }
  if (t == 0) {
    ws->nslots = 0u;
    uint32_t P = total < (uint32_t)TCAP ? total : (uint32_t)TCAP;
    uint32_t M = NM_TOT - P;
    uint32_t npos = P < 128u ? P : 128u;
    ws->P = P; ws->M = M;
    ws->n_pos = npos; ws->n_neg = 256u - npos;
    ws->S[0] = P; ws->S[1] = M;
    ws->kcnt[0] = npos; ws->kcnt[1] = 256u - npos;
    const double LOGU = 22.18070977791825;  // log(2^32 - 1)
    for (int d = 0; d < 2; ++d) {
      uint32_t Sd = ws->S[d];
      int R = 0;
      if (Sd > 1u) {
        R = (int)ceil(3.0 * log((double)Sd) / LOGU);
        if (R < 1) R = 1;
        if (R > 3) R = 3;
      }
      ws->R[d] = (uint32_t)R;
      uint32_t ck0, ck1;
      { uint32_t a = 0u, b = (uint32_t)d; tf2(0u, 42u, a, b); ck0 = a; ck1 = b; }
      for (int rr = 0; rr < 3; ++rr) {
        uint32_t s0 = 0u, s1 = 1u; tf2(ck0, ck1, s0, s1);
        ws->sub[d][rr][0] = s0; ws->sub[d][rr][1] = s1;
        uint32_t n0 = 0u, n1 = 0u; tf2(ck0, ck1, n0, n1);
        ck0 = n0; ck1 = n1;
      }
    }
  }
}

// Ordered emit of true positions (row-major, ascending bit), parallel.
__global__ __launch_bounds__(256) void k_emit(WS* ws) {
  int t = threadIdx.x;
  int row = blockIdx.x * 256 + t;
  ull w = ws->maskWords[row];
  uint32_t c = (uint32_t)__popcll(w);
  __shared__ uint32_t sm[256];
  sm[t] = c;
  __syncthreads();
  for (int off = 1; off < 256; off <<= 1) {
    uint32_t add = (t >= off) ? sm[t - off] : 0u;
    __syncthreads();
    sm[t] += add;
    __syncthreads();
  }
  uint32_t off0 = ws->blockBase[blockIdx.x] + sm[t] - c;
  while (w) {
    int bit = __ffsll((long long)w) - 1;
    w &= (w - 1);
    if (off0 < TCAP) ws->T[off0] = ((uint32_t)row << 6) | (uint32_t)bit;
    off0++;
  }
}

// Threefry scan: LDS histogram + u16 bin-id cache for the gather pass.
__global__ __launch_bounds__(1024) void k_hist(WS* ws, int d, int m) {
  int r = (int)ws->R[d] - m;
  if (r < 1) return;
  __shared__ uint32_t lh[NBINS];
  for (int i = threadIdx.x; i < NBINS; i += blockDim.x) lh[i] = 0u;
  __syncthreads();
  uint32_t S = ws->S[d];
  uint32_t sk0 = ws->sub[d][r - 1][0], sk1 = ws->sub[d][r - 1][1];
  uint32_t stride = gridDim.x * blockDim.x;
  uint32_t j = blockIdx.x * blockDim.x + threadIdx.x;
  for (; j + stride < S; j += 2 * stride) {
    uint32_t k0 = tf_bits(sk0, sk1, j);
    uint32_t k1 = tf_bits(sk0, sk1, j + stride);
    ws->binid[j] = (uint16_t)(k0 >> BINSHIFT);
    ws->binid[j + stride] = (uint16_t)(k1 >> BINSHIFT);
    atomicAdd(&lh[k0 >> BINSHIFT], 1u);
    atomicAdd(&lh[k1 >> BINSHIFT], 1u);
  }
  if (j < S) {
    uint32_t k0 = tf_bits(sk0, sk1, j);
    ws->binid[j] = (uint16_t)(k0 >> BINSHIFT);
    atomicAdd(&lh[k0 >> BINSHIFT], 1u);
  }
  __syncthreads();
  for (int i = threadIdx.x; i < NBINS; i += blockDim.x) {
    uint32_t v = lh[i];
    if (v) atomicAdd(&ws->hist[i], v);
  }
}

// Scan hist in LDS; parallel per-target binary search; CAS-based slot dedup.
// Also clears slotCnt/nslots for this round's gather.
__global__ __launch_bounds__(1024) void k_scanloc(WS* ws, int d, int m) {
  int r = (int)ws->R[d] - m;
  if (r < 1) return;
  __shared__ uint32_t cumS[NBINS + 1];
  __shared__ uint32_t part[1024];
  int t = threadIdx.x;
  if (t == 0) ws->nslots = 0u;
  if (t < MAXSLOT) ws->slotCnt[t] = 0u;
  const int E = NBINS / 1024;  // 8
  uint32_t lv[E];
  uint32_t s = 0;
  uint32_t base = (uint32_t)t * E;
#pragma unroll
  for (int e = 0; e < E; ++e) { lv[e] = ws->hist[base + e]; s += lv[e]; }
  part[t] = s;
  __syncthreads();
  for (int off = 1; off < 1024; off <<= 1) {
    uint32_t add = (t >= off) ? part[t - off] : 0u;
    __syncthreads();
    part[t] += add;
    __syncthreads();
  }
  uint32_t run = part[t] - s;
#pragma unroll
  for (int e = 0; e < E; ++e) { cumS[base + e] = run; run += lv[e]; }
  if (t == 1023) cumS[NBINS] = run;
  __syncthreads();

  uint32_t k = ws->kcnt[d];
  uint32_t lo = 0;
  int old = 0;
  if (t < (int)k) {
    uint32_t tr = ws->tgt[d][t];
    uint32_t hi = NBINS;  // invariant: cumS[lo] <= tr < cumS[hi]
    while (hi - lo > 1u) {
      uint32_t mid = (lo + hi) >> 1;
      if (cumS[mid] <= tr) lo = mid; else hi = mid;
    }
    ws->tlocal[t] = tr - cumS[lo];
    old = atomicCAS(&ws->binslot[lo], -1, (int)(0x10000u + (uint32_t)t));
  }
  __syncthreads();
  if (t < (int)k && old == -1) {
    uint32_t slot = atomicAdd(&ws->nslots, 1u);
    ws->binslot[lo] = (int)slot;
  }
  __syncthreads();
  if (t < (int)k) ws->tslot[t] = ws->binslot[lo];
}

// Phase 1: pure memory scan of u16 bin ids (no threefry), compact hit j's
// into LDS. Phase 2: recompute threefry for hits only (dense, full lanes),
// per-slot range reservation, grouped writes.
__global__ __launch_bounds__(1024) void k_gather(WS* ws, int d, int m) {
  int r = (int)ws->R[d] - m;
  if (r < 1) return;
  __shared__ int bs[NBINS];            // 32KB
  __shared__ uint32_t hk[HCAP];        // 8KB
  __shared__ uint32_t hj[HCAP];        // 8KB
  __shared__ uint32_t scnt[MAXSLOT];
  __shared__ uint32_t sbase[MAXSLOT];
  __shared__ uint32_t scur[MAXSLOT];
  __shared__ uint32_t hcnt;
  int t = threadIdx.x;
  for (int i = t; i < NBINS; i += blockDim.x) bs[i] = ws->binslot[i];
  if (t < MAXSLOT) scnt[t] = 0u;
  if (t == 0) hcnt = 0u;
  __syncthreads();
  uint32_t S = ws->S[d];
  uint32_t sk0 = ws->sub[d][r - 1][0], sk1 = ws->sub[d][r - 1][1];
  uint32_t stride = gridDim.x * blockDim.x;
  for (uint32_t j = blockIdx.x * blockDim.x + t; j < S; j += stride) {
    int sl = bs[ws->binid[j]];
    if (sl >= 0) {
      uint32_t h = atomicAdd(&hcnt, 1u);
      if (h < HCAP) {
        hj[h] = j;
      } else {  // overflow fallback (statistically never)
        uint32_t kk = tf_bits(sk0, sk1, j);
        uint32_t idx = atomicAdd(&ws->slotCnt[sl], 1u);
        if (idx < SLOTCAP) ws->slotBuf[sl][idx] = ((ull)kk << 24) | (ull)j;
      }
    }
  }
  __syncthreads();
  uint32_t n = hcnt < (uint32_t)HCAP ? hcnt : (uint32_t)HCAP;
  // phase 2a: threefry for hits only; count per-slot
  for (uint32_t h = t; h < n; h += blockDim.x) {
    uint32_t kk = tf_bits(sk0, sk1, hj[h]);
    hk[h] = kk;
    atomicAdd(&scnt[bs[kk >> BINSHIFT]], 1u);
  }
  __syncthreads();
  if (t < MAXSLOT) {
    scur[t] = 0u;
    if (scnt[t]) sbase[t] = atomicAdd(&ws->slotCnt[t], scnt[t]);
  }
  __syncthreads();
  for (uint32_t h = t; h < n; h += blockDim.x) {
    uint32_t kk = hk[h], j = hj[h];
    int sl = bs[kk >> BINSHIFT];
    uint32_t idx = sbase[sl] + atomicAdd(&scur[sl], 1u);
    if (idx < SLOTCAP) ws->slotBuf[sl][idx] = ((ull)kk << 24) | (ull)j;
  }
}

// Counting-sort by the 8-bit subkey, then all targets resolve in parallel.
// Also stripes the hist/binslot clear for the NEXT round.
__global__ __launch_bounds__(256) void k_select(WS* ws, int d, int m) {
  int r = (int)ws->R[d] - m;
  if (r < 1) return;
  for (int i = blockIdx.x * 256 + threadIdx.x; i < NBINS; i += MAXSLOT * 256) {
    ws->hist[i] = 0u;
    ws->binslot[i] = -1;
  }
  int slot = blockIdx.x;
  if (slot >= (int)ws->nslots) return;
  int t = threadIdx.x;
  uint32_t cnt = ws->slotCnt[slot];
  if (cnt > SLOTCAP) cnt = SLOTCAP;

  __shared__ ull sh[SLOTCAP];          // 24KB raw
  __shared__ ull srt[SLOTCAP];         // 24KB bucket-grouped
  __shared__ uint32_t hh[256];
  __shared__ uint32_t cum[257];
  __shared__ uint32_t cur[256];
  __shared__ uint32_t sb[256];

  hh[t] = 0u;
  __syncthreads();
  for (uint32_t i = t; i < cnt; i += 256) {
    ull v = ws->slotBuf[slot][i];
    sh[i] = v;
    atomicAdd(&hh[(uint32_t)(v >> 35) & 255u], 1u);
  }
  __syncthreads();
  sb[t] = hh[t];
  __syncthreads();
  for (int off = 1; off < 256; off <<= 1) {
    uint32_t add = (t >= off) ? sb[t - off] : 0u;
    __syncthreads();
    sb[t] += add;
    __syncthreads();
  }
  if (t == 0) cum[0] = 0u;
  cum[t + 1] = sb[t];
  cur[t] = 0u;
  __syncthreads();
  for (uint32_t i = t; i < cnt; i += 256) {
    ull v = sh[i];
    uint32_t b = (uint32_t)(v >> 35) & 255u;
    uint32_t idx = cum[b] + atomicAdd(&cur[b], 1u);
    srt[idx] = v;
  }
  __syncthreads();
  uint32_t k = ws->kcnt[d];
  if (t < (int)k && ws->tslot[t] == slot) {
    uint32_t tr = ws->tlocal[t];
    uint32_t lo = 0, hi = 256;  // invariant: cum[lo] <= tr < cum[hi]
    while (hi - lo > 1u) {
      uint32_t mid = (lo + hi) >> 1;
      if (cum[mid] <= tr) lo = mid; else hi = mid;
    }
    uint32_t r2 = tr - cum[lo];
    uint32_t b0 = cum[lo], b1 = cum[lo + 1];
    for (uint32_t x = b0; x < b1; ++x) {
      ull vx = srt[x];
      uint32_t rank = 0;
      for (uint32_t y = b0; y < b1; ++y) rank += (srt[y] < vx) ? 1u : 0u;
      if (rank == r2) { ws->tgt[d][t] = (uint32_t)(vx & 0xFFFFFFull); break; }
    }
  }
}

__device__ __forceinline__ float sl1(float dd) {
  float ad = fabsf(dd);
  return (ad < 1.0f) ? 0.5f * dd * dd : ad - 0.5f;
}

__global__ __launch_bounds__(256) void k_loss(WS* ws,
                                              const float* __restrict__ reg,
                                              const float* __restrict__ obj,
                                              const float4* __restrict__ tgtb,
                                              const float4* __restrict__ anch,
                                              float* out) {
  int s = threadIdx.x;
  uint32_t npos = ws->n_pos;
  double lr = 0.0, bc = 0.0;
  if (s < (int)npos) {
    uint32_t v = ws->tgt[0][s];
    uint32_t pa = ws->T[v];
    uint32_t i = pa >> 6, j = pa & 63u;
    float4 t = tgtb[j];
    float tcx = (t.x + t.z) * 0.5f, tcy = (t.y + t.w) * 0.5f;
    float tw = t.z - t.x, th = t.w - t.y;
    float4 a = anch[i];
    float r0 = (tcx - a.x) / a.z;
    float r1 = (tcy - a.y) / a.w;
    float r2 = logf(tw / a.z);
    float r3 = logf(th / a.w);
    lr = (double)sl1(reg[i * 4 + 0] - r0) + (double)sl1(reg[i * 4 + 1] - r1) +
         (double)sl1(reg[i * 4 + 2] - r2) + (double)sl1(reg[i * 4 + 3] - r3);
    float x = obj[i];
    bc = (double)(fmaxf(x, 0.0f) - x + log1pf(expf(-fabsf(x))));
  } else {
    uint32_t e = ws->tgt[1][s - (int)npos];
    uint32_t f = e;
    uint32_t P = ws->P;
    for (uint32_t q = 0; q < P; ++q) {
      if (ws->T[q] <= f) f++; else break;
    }
    uint32_t i = f >> 6;
    float x = obj[i];
    bc = (double)(fmaxf(x, 0.0f) + log1pf(expf(-fabsf(x))));
  }
  __shared__ double sA[256], sB[256];
  sA[s] = lr; sB[s] = bc;
  __syncthreads();
  for (int off = 128; off > 0; off >>= 1) {
    if (s < off) { sA[s] += sA[s + off]; sB[s] += sB[s + off]; }
    __syncthreads();
  }
  if (s == 0)
    out[0] = (float)(sA[0] * (10.0 / 2500.0) + sB[0] * (1.0 / 256.0));
}

extern "C" void kernel_launch(void* const* d_in, const int* in_sizes, int n_in,
                              void* d_out, int out_size, void* d_ws,
                              size_t ws_size, hipStream_t stream) {
  const float*  reg  = (const float*)d_in[0];
  const float*  obj  = (const float*)d_in[1];
  const float4* pred = (const float4*)d_in[2];
  const float4* tgtb = (const float4*)d_in[3];
  const float4* anch = (const float4*)d_in[4];
  float* out = (float*)d_out;
  WS* ws = (WS*)d_ws;
  (void)in_sizes; (void)n_in; (void)out_size; (void)ws_size;

  k_init<<<1, 64, 0, stream>>>(ws);
  k_iou<<<N_PRED / 256, 256, 0, stream>>>(pred, tgtb, ws);
  k_fix<<<1, 64, 0, stream>>>(ws);
  k_cnt<<<CBLK, 256, 0, stream>>>(ws);
  k_setup<<<1, 512, 0, stream>>>(ws);
  k_emit<<<CBLK, 256, 0, stream>>>(ws);
  for (int d = 0; d < 2; ++d) {
    int hb = (d == 0) ? 32 : 256;          // pos chain is tiny (S = P)
    int ht = (d == 0) ? 256 : 1024;
    for (int m = 0; m < 3; ++m) {
      k_hist<<<hb, ht, 0, stream>>>(ws, d, m);
      k_scanloc<<<1, 1024, 0, stream>>>(ws, d, m);
      k_gather<<<hb, ht, 0, stream>>>(ws, d, m);
      k_select<<<MAXSLOT, 256, 0, stream>>>(ws, d, m);
    }
  }
  k_loss<<<1, 256, 0, stream>>>(ws, reg, obj, tgtb, anch, out);
}